// Round 1
// baseline (2764.152 us; speedup 1.0000x reference)
//
#include <hip/hip_runtime.h>

#define D 128
#define TM 32

// Wc = Vkx_w - 2*Wkx_w ; bc = Vkx_b - 2*Wkx_b   (folds 2 GEMMs + 1 SpMM away)
__global__ void combine_w_kernel(const float* __restrict__ Vw, const float* __restrict__ Ww,
                                 const float* __restrict__ Vb, const float* __restrict__ Wb,
                                 float* __restrict__ Wc, float* __restrict__ bc) {
    int i = blockIdx.x * blockDim.x + threadIdx.x;
    if (i < D * D) Wc[i] = Vw[i] - 2.0f * Ww[i];
    if (i < D) bc[i] = Vb[i] - 2.0f * Wb[i];
}

// out = relu_epilogue( X @ W^T + bias )
// EPI=0: out = X@W^T + bias
// EPI=1: out = relu(acc + bias - s*(colvec[r] - spout[r][c]))   (x update)
// EPI=2: out = relu(acc + bias - s*(colvec[r] + spout[r][c]))   (y update)
template <int EPI>
__global__ __launch_bounds__(256) void gemm_fused(
    const float* __restrict__ X, const float* __restrict__ W,
    const float* __restrict__ bias, const float* __restrict__ colvec,
    const float* __restrict__ spout, const float* __restrict__ scal,
    float* __restrict__ out, int N)
{
    __shared__ float Wt[64][D + 4];   // W transposed, k-tile of 64; +4 pad keeps 16B align, breaks stride
    __shared__ float Xs[TM][D + 4];
    const int t = threadIdx.x;
    const int block_row = blockIdx.x * TM;

    // stage X tile (coalesced float4)
#pragma unroll
    for (int i = 0; i < 4; ++i) {
        int f = t + i * 256;          // 1024 float4 = 32 rows x 128
        int r = f >> 5;
        int k4 = (f & 31) << 2;
        float4 g = make_float4(0.f, 0.f, 0.f, 0.f);
        int row = block_row + r;
        if (row < N) g = *reinterpret_cast<const float4*>(&X[(size_t)row * D + k4]);
        *reinterpret_cast<float4*>(&Xs[r][k4]) = g;
    }

    const int cg = t & 15;            // 16 col-groups
    const int rp = t >> 4;            // 16 row-pairs
    const int r0 = rp * 2, r1 = r0 + 1;
    const int c0 = cg * 4, c1 = 64 + cg * 4;   // split cols -> 2-way (free) LDS banking

    float acc[2][2][4] = {{{0.f}}};

    for (int kb = 0; kb < D; kb += 64) {
        __syncthreads();
        // stage Wt[kk][d] = W[d][kb+kk]  (transpose in LDS)
#pragma unroll
        for (int i = 0; i < 8; ++i) {
            int f = t + i * 256;      // 2048 float4
            int d = f >> 4;
            int kk = (f & 15) << 2;
            float4 g = *reinterpret_cast<const float4*>(&W[d * D + kb + kk]);
            Wt[kk + 0][d] = g.x;
            Wt[kk + 1][d] = g.y;
            Wt[kk + 2][d] = g.z;
            Wt[kk + 3][d] = g.w;
        }
        __syncthreads();
#pragma unroll 8
        for (int kk = 0; kk < 64; ++kk) {
            float xa = Xs[r0][kb + kk];
            float xb = Xs[r1][kb + kk];
            float4 w0 = *reinterpret_cast<float4*>(&Wt[kk][c0]);
            float4 w1 = *reinterpret_cast<float4*>(&Wt[kk][c1]);
            acc[0][0][0] += xa * w0.x; acc[0][0][1] += xa * w0.y;
            acc[0][0][2] += xa * w0.z; acc[0][0][3] += xa * w0.w;
            acc[0][1][0] += xa * w1.x; acc[0][1][1] += xa * w1.y;
            acc[0][1][2] += xa * w1.z; acc[0][1][3] += xa * w1.w;
            acc[1][0][0] += xb * w0.x; acc[1][0][1] += xb * w0.y;
            acc[1][0][2] += xb * w0.z; acc[1][0][3] += xb * w0.w;
            acc[1][1][0] += xb * w1.x; acc[1][1][1] += xb * w1.y;
            acc[1][1][2] += xb * w1.z; acc[1][1][3] += xb * w1.w;
        }
    }

    const float sc = (EPI == 0) ? 0.f : scal[0];
    const float4 bias0 = *reinterpret_cast<const float4*>(&bias[c0]);
    const float4 bias1 = *reinterpret_cast<const float4*>(&bias[c1]);

#pragma unroll
    for (int ri = 0; ri < 2; ++ri) {
        const int row = block_row + (ri == 0 ? r0 : r1);
        if (row >= N) continue;
        const float cv = (EPI == 0) ? 0.f : colvec[row];
#pragma unroll
        for (int h = 0; h < 2; ++h) {
            const int col = (h == 0) ? c0 : c1;
            const float4 bs = (h == 0) ? bias0 : bias1;
            float4 res;
            res.x = acc[ri][h][0] + bs.x;
            res.y = acc[ri][h][1] + bs.y;
            res.z = acc[ri][h][2] + bs.z;
            res.w = acc[ri][h][3] + bs.w;
            if (EPI == 1) {
                float4 sp = *reinterpret_cast<const float4*>(&spout[(size_t)row * D + col]);
                res.x = fmaxf(res.x - sc * (cv - sp.x), 0.f);
                res.y = fmaxf(res.y - sc * (cv - sp.y), 0.f);
                res.z = fmaxf(res.z - sc * (cv - sp.z), 0.f);
                res.w = fmaxf(res.w - sc * (cv - sp.w), 0.f);
            } else if (EPI == 2) {
                float4 sp = *reinterpret_cast<const float4*>(&spout[(size_t)row * D + col]);
                res.x = fmaxf(res.x - sc * (cv + sp.x), 0.f);
                res.y = fmaxf(res.y - sc * (cv + sp.y), 0.f);
                res.z = fmaxf(res.z - sc * (cv + sp.z), 0.f);
                res.w = fmaxf(res.w - sc * (cv + sp.w), 0.f);
            }
            *reinterpret_cast<float4*>(&out[(size_t)row * D + col]) = res;
        }
    }
}

// out[orow[e]] += vals[e] * X[gcol[e]]   -- one wave per edge, 2 floats/lane
__global__ __launch_bounds__(256) void spmm_atomic(
    const float* __restrict__ vals, const int* __restrict__ orow,
    const int* __restrict__ gcol, const float* __restrict__ Xm,
    float* __restrict__ outm, int nnz)
{
    const int gwave = (blockIdx.x * 256 + threadIdx.x) >> 6;
    const int lane = threadIdx.x & 63;
    const int e0 = gwave * 4;
#pragma unroll
    for (int i = 0; i < 4; ++i) {
        int e = e0 + i;
        if (e >= nnz) break;
        float v = vals[e];
        int r = orow[e];
        int c = gcol[e];
        float2 xv = *reinterpret_cast<const float2*>(&Xm[(size_t)c * D + lane * 2]);
        unsafeAtomicAdd(&outm[(size_t)r * D + lane * 2 + 0], v * xv.x);
        unsafeAtomicAdd(&outm[(size_t)r * D + lane * 2 + 1], v * xv.y);
    }
}

extern "C" void kernel_launch(void* const* d_in, const int* in_sizes, int n_in,
                              void* d_out, int out_size, void* d_ws, size_t ws_size,
                              hipStream_t stream) {
    const float* x      = (const float*)d_in[0];
    const float* y      = (const float*)d_in[1];
    const float* c      = (const float*)d_in[2];
    const float* b      = (const float*)d_in[3];
    const float* A_vals = (const float*)d_in[4];
    const int*   A_rows = (const int*)d_in[5];
    const int*   A_cols = (const int*)d_in[6];
    const float* Ukx_w  = (const float*)d_in[7];
    const float* Ukx_b  = (const float*)d_in[8];
    const float* Uky_w  = (const float*)d_in[9];
    const float* Uky_b  = (const float*)d_in[10];
    const float* tau    = (const float*)d_in[11];
    const float* Vky_w  = (const float*)d_in[12];
    const float* Vky_b  = (const float*)d_in[13];
    const float* Wkx_w  = (const float*)d_in[14];
    const float* Wkx_b  = (const float*)d_in[15];
    const float* Vkx_w  = (const float*)d_in[16];
    const float* Vkx_b  = (const float*)d_in[17];
    const float* sigma  = (const float*)d_in[18];

    const int N   = in_sizes[0] / D;   // 50000
    const int nnz = in_sizes[4];       // 1.6M

    float* out_x = (float*)d_out;                 // x_new; also at_uy accumulator
    float* out_y = out_x + (size_t)N * D;         // y_new; also az accumulator
    float* tmp   = (float*)d_ws;                  // uy, then zx  (N*D floats)
    float* Wc    = tmp + (size_t)N * D;
    float* bc    = Wc + D * D;

    const int gemm_grid = (N + TM - 1) / TM;
    const int spmm_grid = (nnz + 15) / 16;        // 4 edges/wave, 4 waves/block

    // fold Vkx - 2*Wkx
    combine_w_kernel<<<(D * D + 255) / 256, 256, 0, stream>>>(Vkx_w, Wkx_w, Vkx_b, Wkx_b, Wc, bc);

    // uy = y @ Uky^T + Uky_b
    gemm_fused<0><<<gemm_grid, 256, 0, stream>>>(y, Uky_w, Uky_b, nullptr, nullptr, nullptr, tmp, N);

    // at_uy = A^T @ uy   (accumulate in out_x)
    hipMemsetAsync(out_x, 0, (size_t)N * D * sizeof(float), stream);
    spmm_atomic<<<spmm_grid, 256, 0, stream>>>(A_vals, A_cols, A_rows, tmp, out_x, nnz);

    // x_new = relu(x@Ukx^T + Ukx_b - tau*(c - at_uy))   (in-place epilogue over out_x)
    gemm_fused<1><<<gemm_grid, 256, 0, stream>>>(x, Ukx_w, Ukx_b, c, out_x, tau, out_x, N);

    // zx = x_new @ Wc^T + bc
    gemm_fused<0><<<gemm_grid, 256, 0, stream>>>(out_x, Wc, bc, nullptr, nullptr, nullptr, tmp, N);

    // az = A @ zx   (accumulate in out_y)
    hipMemsetAsync(out_y, 0, (size_t)N * D * sizeof(float), stream);
    spmm_atomic<<<spmm_grid, 256, 0, stream>>>(A_vals, A_rows, A_cols, tmp, out_y, nnz);

    // y_new = relu(y@Vky^T + Vky_b - sigma*(b + az))
    gemm_fused<2><<<gemm_grid, 256, 0, stream>>>(y, Vky_w, Vky_b, b, out_y, sigma, out_y, N);
}

// Round 2
// 830.014 us; speedup vs baseline: 3.3302x; 3.3302x over previous
//
#include <hip/hip_runtime.h>

#define D 128
#define TM 32

// ---------------- weight fold: Wc = Vkx_w - 2*Wkx_w ----------------
__global__ void combine_w_kernel(const float* __restrict__ Vw, const float* __restrict__ Ww,
                                 const float* __restrict__ Vb, const float* __restrict__ Wb,
                                 float* __restrict__ Wc, float* __restrict__ bc) {
    int i = blockIdx.x * blockDim.x + threadIdx.x;
    if (i < D * D) Wc[i] = Vw[i] - 2.0f * Ww[i];
    if (i < D) bc[i] = Vb[i] - 2.0f * Wb[i];
}

// ---------------- fused GEMM out = epi(X @ W^T + bias) ----------------
template <int EPI>
__global__ __launch_bounds__(256) void gemm_fused(
    const float* __restrict__ X, const float* __restrict__ W,
    const float* __restrict__ bias, const float* __restrict__ colvec,
    const float* __restrict__ spout, const float* __restrict__ scal,
    float* __restrict__ out, int N)
{
    __shared__ float Wt[64][D + 4];
    __shared__ float Xs[TM][D + 4];
    const int t = threadIdx.x;
    const int block_row = blockIdx.x * TM;

#pragma unroll
    for (int i = 0; i < 4; ++i) {
        int f = t + i * 256;
        int r = f >> 5;
        int k4 = (f & 31) << 2;
        float4 g = make_float4(0.f, 0.f, 0.f, 0.f);
        int row = block_row + r;
        if (row < N) g = *reinterpret_cast<const float4*>(&X[(size_t)row * D + k4]);
        *reinterpret_cast<float4*>(&Xs[r][k4]) = g;
    }

    const int cg = t & 15;
    const int rp = t >> 4;
    const int r0 = rp * 2, r1 = r0 + 1;
    const int c0 = cg * 4, c1 = 64 + cg * 4;

    float acc[2][2][4] = {{{0.f}}};

    for (int kb = 0; kb < D; kb += 64) {
        __syncthreads();
#pragma unroll
        for (int i = 0; i < 8; ++i) {
            int f = t + i * 256;
            int d = f >> 4;
            int kk = (f & 15) << 2;
            float4 g = *reinterpret_cast<const float4*>(&W[d * D + kb + kk]);
            Wt[kk + 0][d] = g.x;
            Wt[kk + 1][d] = g.y;
            Wt[kk + 2][d] = g.z;
            Wt[kk + 3][d] = g.w;
        }
        __syncthreads();
#pragma unroll 8
        for (int kk = 0; kk < 64; ++kk) {
            float xa = Xs[r0][kb + kk];
            float xb = Xs[r1][kb + kk];
            float4 w0 = *reinterpret_cast<float4*>(&Wt[kk][c0]);
            float4 w1 = *reinterpret_cast<float4*>(&Wt[kk][c1]);
            acc[0][0][0] += xa * w0.x; acc[0][0][1] += xa * w0.y;
            acc[0][0][2] += xa * w0.z; acc[0][0][3] += xa * w0.w;
            acc[0][1][0] += xa * w1.x; acc[0][1][1] += xa * w1.y;
            acc[0][1][2] += xa * w1.z; acc[0][1][3] += xa * w1.w;
            acc[1][0][0] += xb * w0.x; acc[1][0][1] += xb * w0.y;
            acc[1][0][2] += xb * w0.z; acc[1][0][3] += xb * w0.w;
            acc[1][1][0] += xb * w1.x; acc[1][1][1] += xb * w1.y;
            acc[1][1][2] += xb * w1.z; acc[1][1][3] += xb * w1.w;
        }
    }

    const float sc = (EPI == 0) ? 0.f : scal[0];
    const float4 bias0 = *reinterpret_cast<const float4*>(&bias[c0]);
    const float4 bias1 = *reinterpret_cast<const float4*>(&bias[c1]);

#pragma unroll
    for (int ri = 0; ri < 2; ++ri) {
        const int row = block_row + (ri == 0 ? r0 : r1);
        if (row >= N) continue;
        const float cv = (EPI == 0) ? 0.f : colvec[row];
#pragma unroll
        for (int h = 0; h < 2; ++h) {
            const int col = (h == 0) ? c0 : c1;
            const float4 bs = (h == 0) ? bias0 : bias1;
            float4 res;
            res.x = acc[ri][h][0] + bs.x;
            res.y = acc[ri][h][1] + bs.y;
            res.z = acc[ri][h][2] + bs.z;
            res.w = acc[ri][h][3] + bs.w;
            if (EPI == 1) {
                float4 sp = *reinterpret_cast<const float4*>(&spout[(size_t)row * D + col]);
                res.x = fmaxf(res.x - sc * (cv - sp.x), 0.f);
                res.y = fmaxf(res.y - sc * (cv - sp.y), 0.f);
                res.z = fmaxf(res.z - sc * (cv - sp.z), 0.f);
                res.w = fmaxf(res.w - sc * (cv - sp.w), 0.f);
            } else if (EPI == 2) {
                float4 sp = *reinterpret_cast<const float4*>(&spout[(size_t)row * D + col]);
                res.x = fmaxf(res.x - sc * (cv + sp.x), 0.f);
                res.y = fmaxf(res.y - sc * (cv + sp.y), 0.f);
                res.z = fmaxf(res.z - sc * (cv + sp.z), 0.f);
                res.w = fmaxf(res.w - sc * (cv + sp.w), 0.f);
            }
            *reinterpret_cast<float4*>(&out[(size_t)row * D + col]) = res;
        }
    }
}

// ---------------- CSR build ----------------
__global__ __launch_bounds__(256) void hist_kernel(const int* __restrict__ orow,
                                                   int* __restrict__ cnt, int nnz) {
    int e = blockIdx.x * 256 + threadIdx.x;
    if (e < nnz) atomicAdd(&cnt[orow[e]], 1);
}

// per-block exclusive scan (Hillis-Steele inclusive, then subtract self)
__global__ __launch_bounds__(256) void scan_block(const int* __restrict__ in,
                                                  int* __restrict__ out,
                                                  int* __restrict__ bsum, int n) {
    __shared__ int s[256];
    int i = blockIdx.x * 256 + threadIdx.x;
    int v = (i < n) ? in[i] : 0;
    s[threadIdx.x] = v;
    __syncthreads();
#pragma unroll
    for (int d = 1; d < 256; d <<= 1) {
        int t = (threadIdx.x >= d) ? s[threadIdx.x - d] : 0;
        __syncthreads();
        s[threadIdx.x] += t;
        __syncthreads();
    }
    if (i < n) out[i] = s[threadIdx.x] - v;
    if (threadIdx.x == 255 && bsum) bsum[blockIdx.x] = s[255];
}

__global__ __launch_bounds__(256) void scan_bsum(int* __restrict__ bsum, int nb) {
    __shared__ int s[256];
    int v = (threadIdx.x < nb) ? bsum[threadIdx.x] : 0;
    s[threadIdx.x] = v;
    __syncthreads();
#pragma unroll
    for (int d = 1; d < 256; d <<= 1) {
        int t = (threadIdx.x >= d) ? s[threadIdx.x - d] : 0;
        __syncthreads();
        s[threadIdx.x] += t;
        __syncthreads();
    }
    if (threadIdx.x < nb) bsum[threadIdx.x] = s[threadIdx.x] - v;  // exclusive
}

__global__ __launch_bounds__(256) void add_bsum(int* __restrict__ off,
                                                const int* __restrict__ bsum, int n) {
    int i = blockIdx.x * 256 + threadIdx.x;
    if (i < n) off[i] += bsum[blockIdx.x];
}

__global__ __launch_bounds__(256) void scatter_kernel(const int* __restrict__ orow,
                                                      const int* __restrict__ off,
                                                      int* __restrict__ cnt2,
                                                      int* __restrict__ perm, int nnz) {
    int e = blockIdx.x * 256 + threadIdx.x;
    if (e < nnz) {
        int r = orow[e];
        int p = off[r] + atomicAdd(&cnt2[r], 1);
        perm[p] = e;
    }
}

// ---------------- gather SpMM: out[row] = sum_e vals[e]*X[gcol[e]] ----------------
__global__ __launch_bounds__(256) void spmm_gather(
    const float* __restrict__ vals, const int* __restrict__ gcol,
    const int* __restrict__ perm, const int* __restrict__ off,
    const int* __restrict__ len, const float* __restrict__ X,
    float* __restrict__ out, int N)
{
    const int row = (blockIdx.x * 256 + threadIdx.x) >> 6;
    if (row >= N) return;
    const int lane = threadIdx.x & 63;
    const int s = off[row];
    const int L = len[row];

    float ax = 0.f, ay = 0.f, bx = 0.f, by = 0.f;
    int i = 0;
    for (; i + 1 < L; i += 2) {
        int e0 = perm[s + i];
        int e1 = perm[s + i + 1];
        float v0 = vals[e0];
        float v1 = vals[e1];
        int c0 = gcol[e0];
        int c1 = gcol[e1];
        float2 x0 = *reinterpret_cast<const float2*>(&X[(size_t)c0 * D + lane * 2]);
        float2 x1 = *reinterpret_cast<const float2*>(&X[(size_t)c1 * D + lane * 2]);
        ax += v0 * x0.x; ay += v0 * x0.y;
        bx += v1 * x1.x; by += v1 * x1.y;
    }
    if (i < L) {
        int e0 = perm[s + i];
        float v0 = vals[e0];
        int c0 = gcol[e0];
        float2 x0 = *reinterpret_cast<const float2*>(&X[(size_t)c0 * D + lane * 2]);
        ax += v0 * x0.x; ay += v0 * x0.y;
    }
    float2 res = make_float2(ax + bx, ay + by);
    *reinterpret_cast<float2*>(&out[(size_t)row * D + lane * 2]) = res;
}

// ---------------- fallback atomic SpMM (round-1 proven) ----------------
__global__ __launch_bounds__(256) void spmm_atomic(
    const float* __restrict__ vals, const int* __restrict__ orow,
    const int* __restrict__ gcol, const float* __restrict__ Xm,
    float* __restrict__ outm, int nnz)
{
    const int gwave = (blockIdx.x * 256 + threadIdx.x) >> 6;
    const int lane = threadIdx.x & 63;
    const int e0 = gwave * 4;
#pragma unroll
    for (int i = 0; i < 4; ++i) {
        int e = e0 + i;
        if (e >= nnz) break;
        float v = vals[e];
        int r = orow[e];
        int c = gcol[e];
        float2 xv = *reinterpret_cast<const float2*>(&Xm[(size_t)c * D + lane * 2]);
        unsafeAtomicAdd(&outm[(size_t)r * D + lane * 2 + 0], v * xv.x);
        unsafeAtomicAdd(&outm[(size_t)r * D + lane * 2 + 1], v * xv.y);
    }
}

extern "C" void kernel_launch(void* const* d_in, const int* in_sizes, int n_in,
                              void* d_out, int out_size, void* d_ws, size_t ws_size,
                              hipStream_t stream) {
    const float* x      = (const float*)d_in[0];
    const float* y      = (const float*)d_in[1];
    const float* c      = (const float*)d_in[2];
    const float* b      = (const float*)d_in[3];
    const float* A_vals = (const float*)d_in[4];
    const int*   A_rows = (const int*)d_in[5];
    const int*   A_cols = (const int*)d_in[6];
    const float* Ukx_w  = (const float*)d_in[7];
    const float* Ukx_b  = (const float*)d_in[8];
    const float* Uky_w  = (const float*)d_in[9];
    const float* Uky_b  = (const float*)d_in[10];
    const float* tau    = (const float*)d_in[11];
    const float* Vky_w  = (const float*)d_in[12];
    const float* Vky_b  = (const float*)d_in[13];
    const float* Wkx_w  = (const float*)d_in[14];
    const float* Wkx_b  = (const float*)d_in[15];
    const float* Vkx_w  = (const float*)d_in[16];
    const float* Vkx_b  = (const float*)d_in[17];
    const float* sigma  = (const float*)d_in[18];

    const int N   = in_sizes[0] / D;   // 50000
    const int nnz = in_sizes[4];       // 1.6M
    const int nblocks = (N + 255) / 256;

    float* out_x = (float*)d_out;
    float* out_y = out_x + (size_t)N * D;

    const int gemm_grid = (N + TM - 1) / TM;

    // ws layout (gather path): tmp[N*D] | Wc[D*D] | bc[D] | cnt[N] | cnt2[N] | off[N] | bsum[256] | perm[nnz]
    size_t need = ((size_t)N * D + D * D + D + 3 * (size_t)N + 256 + (size_t)nnz) * 4;
    const bool gather_ok = (ws_size >= need) && (nblocks <= 256);

    float* tmp = (float*)d_ws;
    float* Wc  = tmp + (size_t)N * D;
    float* bc  = Wc + D * D;
    int*   cnt  = (int*)(bc + D);
    int*   cnt2 = cnt + N;
    int*   off  = cnt2 + N;
    int*   bsum = off + N;
    int*   perm = bsum + 256;

    combine_w_kernel<<<(D * D + 255) / 256, 256, 0, stream>>>(Vkx_w, Wkx_w, Vkx_b, Wkx_b, Wc, bc);

    if (gather_ok) {
        const int egrid = (nnz + 255) / 256;
        const int ggrid = (N + 3) / 4;   // 4 rows (waves) per block

        // uy = y @ Uky^T + Uky_b  -> staged in out_y (free until the end)
        gemm_fused<0><<<gemm_grid, 256, 0, stream>>>(y, Uky_w, Uky_b, nullptr, nullptr, nullptr, out_y, N);

        // ---- build grouping by A_cols (for A^T spmm) ----
        hipMemsetAsync(cnt, 0, (size_t)N * sizeof(int), stream);
        hipMemsetAsync(cnt2, 0, (size_t)N * sizeof(int), stream);
        hist_kernel<<<egrid, 256, 0, stream>>>(A_cols, cnt, nnz);
        scan_block<<<nblocks, 256, 0, stream>>>(cnt, off, bsum, N);
        scan_bsum<<<1, 256, 0, stream>>>(bsum, nblocks);
        add_bsum<<<nblocks, 256, 0, stream>>>(off, bsum, N);
        scatter_kernel<<<egrid, 256, 0, stream>>>(A_cols, off, cnt2, perm, nnz);

        // at_uy -> out_x
        spmm_gather<<<ggrid, 256, 0, stream>>>(A_vals, A_rows, perm, off, cnt, out_y, out_x, N);

        // x_new = relu(x@Ukx^T + b - tau*(c - at_uy)) -> out_x (in place)
        gemm_fused<1><<<gemm_grid, 256, 0, stream>>>(x, Ukx_w, Ukx_b, c, out_x, tau, out_x, N);

        // zx = x_new @ Wc^T + bc -> tmp
        gemm_fused<0><<<gemm_grid, 256, 0, stream>>>(out_x, Wc, bc, nullptr, nullptr, nullptr, tmp, N);

        // ---- build grouping by A_rows (for A spmm) ----
        hipMemsetAsync(cnt, 0, (size_t)N * sizeof(int), stream);
        hipMemsetAsync(cnt2, 0, (size_t)N * sizeof(int), stream);
        hist_kernel<<<egrid, 256, 0, stream>>>(A_rows, cnt, nnz);
        scan_block<<<nblocks, 256, 0, stream>>>(cnt, off, bsum, N);
        scan_bsum<<<1, 256, 0, stream>>>(bsum, nblocks);
        add_bsum<<<nblocks, 256, 0, stream>>>(off, bsum, N);
        scatter_kernel<<<egrid, 256, 0, stream>>>(A_rows, off, cnt2, perm, nnz);

        // az -> out_y  (reads zx from tmp; uy already consumed)
        spmm_gather<<<ggrid, 256, 0, stream>>>(A_vals, A_cols, perm, off, cnt, tmp, out_y, N);

        // y_new = relu(y@Vky^T + b - sigma*(b_vec + az)) -> out_y (in place)
        gemm_fused<2><<<gemm_grid, 256, 0, stream>>>(y, Vky_w, Vky_b, b, out_y, sigma, out_y, N);
    } else {
        // fallback: round-1 atomic path
        const int spmm_grid = (nnz + 15) / 16;
        gemm_fused<0><<<gemm_grid, 256, 0, stream>>>(y, Uky_w, Uky_b, nullptr, nullptr, nullptr, tmp, N);
        hipMemsetAsync(out_x, 0, (size_t)N * D * sizeof(float), stream);
        spmm_atomic<<<spmm_grid, 256, 0, stream>>>(A_vals, A_cols, A_rows, tmp, out_x, nnz);
        gemm_fused<1><<<gemm_grid, 256, 0, stream>>>(x, Ukx_w, Ukx_b, c, out_x, tau, out_x, N);
        gemm_fused<0><<<gemm_grid, 256, 0, stream>>>(out_x, Wc, bc, nullptr, nullptr, nullptr, tmp, N);
        hipMemsetAsync(out_y, 0, (size_t)N * D * sizeof(float), stream);
        spmm_atomic<<<spmm_grid, 256, 0, stream>>>(A_vals, A_rows, A_cols, tmp, out_y, nnz);
        gemm_fused<2><<<gemm_grid, 256, 0, stream>>>(y, Vky_w, Vky_b, b, out_y, sigma, out_y, N);
    }
}

// Round 3
// 651.922 us; speedup vs baseline: 4.2400x; 1.2732x over previous
//
#include <hip/hip_runtime.h>

#define D 128

// ---------------- weight fold: Wc = Vkx_w - 2*Wkx_w ----------------
__global__ void combine_w_kernel(const float* __restrict__ Vw, const float* __restrict__ Ww,
                                 const float* __restrict__ Vb, const float* __restrict__ Wb,
                                 float* __restrict__ Wc, float* __restrict__ bc) {
    int i = blockIdx.x * blockDim.x + threadIdx.x;
    if (i < D * D) Wc[i] = Vw[i] - 2.0f * Ww[i];
    if (i < D) bc[i] = Vb[i] - 2.0f * Wb[i];
}

// ---------------- fused GEMM: out = epi(X @ W^T + bias) ----------------
// 64 rows x 128 cols per block (256 thr); per thread 4 rows x 8 cols.
// EPI=0: out = acc + bias
// EPI=1: out = relu(acc + bias - s*(colvec[r] - sp))
// EPI=2: out = relu(acc + bias - s*(colvec[r] + sp))
template <int EPI>
__global__ __launch_bounds__(256) void gemm_fused(
    const float* __restrict__ X, const float* __restrict__ W,
    const float* __restrict__ bias, const float* __restrict__ colvec,
    const float* __restrict__ spout, const float* __restrict__ scal,
    float* __restrict__ out, int N)
{
    __shared__ float Xs[64][D + 4];   // full K rows, 33.8 KB
    __shared__ float Wt[64][D + 4];   // transposed W k-tile, 33.8 KB
    const int t = threadIdx.x;
    const int block_row = blockIdx.x * 64;

    // stage X tile once (all 128 k)
#pragma unroll
    for (int i = 0; i < 8; ++i) {
        int f = t + i * 256;          // 2048 float4
        int r = f >> 5;               // 0..63
        int k4 = (f & 31) << 2;       // 0..124
        float4 g = make_float4(0.f, 0.f, 0.f, 0.f);
        int row = block_row + r;
        if (row < N) g = *reinterpret_cast<const float4*>(&X[(size_t)row * D + k4]);
        *reinterpret_cast<float4*>(&Xs[r][k4]) = g;
    }

    const int cg = t & 15;
    const int rp = t >> 4;
    const int r0 = rp * 4;
    const int c0 = cg * 4, c1 = 64 + cg * 4;

    float acc[4][8];
#pragma unroll
    for (int j = 0; j < 4; ++j)
#pragma unroll
        for (int h = 0; h < 8; ++h) acc[j][h] = 0.f;

    for (int kb = 0; kb < D; kb += 64) {
        __syncthreads();
        // stage Wt[kk][d] = W[d][kb+kk]
#pragma unroll
        for (int i = 0; i < 8; ++i) {
            int f = t + i * 256;
            int d = f >> 4;           // 0..127
            int k4 = (f & 15) << 2;   // 0..60
            float4 g = *reinterpret_cast<const float4*>(&W[d * D + kb + k4]);
            Wt[k4 + 0][d] = g.x;
            Wt[k4 + 1][d] = g.y;
            Wt[k4 + 2][d] = g.z;
            Wt[k4 + 3][d] = g.w;
        }
        __syncthreads();
#pragma unroll 4
        for (int kk = 0; kk < 64; ++kk) {
            float4 w0 = *reinterpret_cast<const float4*>(&Wt[kk][c0]);
            float4 w1 = *reinterpret_cast<const float4*>(&Wt[kk][c1]);
#pragma unroll
            for (int j = 0; j < 4; ++j) {
                float xv = Xs[r0 + j][kb + kk];
                acc[j][0] += xv * w0.x; acc[j][1] += xv * w0.y;
                acc[j][2] += xv * w0.z; acc[j][3] += xv * w0.w;
                acc[j][4] += xv * w1.x; acc[j][5] += xv * w1.y;
                acc[j][6] += xv * w1.z; acc[j][7] += xv * w1.w;
            }
        }
    }

    const float sc = (EPI == 0) ? 0.f : scal[0];
    const float4 bias0 = *reinterpret_cast<const float4*>(&bias[c0]);
    const float4 bias1 = *reinterpret_cast<const float4*>(&bias[c1]);

#pragma unroll
    for (int j = 0; j < 4; ++j) {
        const int row = block_row + r0 + j;
        if (row >= N) continue;
        const float cv = (EPI == 0) ? 0.f : colvec[row];
#pragma unroll
        for (int h = 0; h < 2; ++h) {
            const int col = (h == 0) ? c0 : c1;
            const float4 bs = (h == 0) ? bias0 : bias1;
            float4 res;
            res.x = acc[j][h * 4 + 0] + bs.x;
            res.y = acc[j][h * 4 + 1] + bs.y;
            res.z = acc[j][h * 4 + 2] + bs.z;
            res.w = acc[j][h * 4 + 3] + bs.w;
            if (EPI == 1) {
                float4 sp = *reinterpret_cast<const float4*>(&spout[(size_t)row * D + col]);
                res.x = fmaxf(res.x - sc * (cv - sp.x), 0.f);
                res.y = fmaxf(res.y - sc * (cv - sp.y), 0.f);
                res.z = fmaxf(res.z - sc * (cv - sp.z), 0.f);
                res.w = fmaxf(res.w - sc * (cv - sp.w), 0.f);
            } else if (EPI == 2) {
                float4 sp = *reinterpret_cast<const float4*>(&spout[(size_t)row * D + col]);
                res.x = fmaxf(res.x - sc * (cv + sp.x), 0.f);
                res.y = fmaxf(res.y - sc * (cv + sp.y), 0.f);
                res.z = fmaxf(res.z - sc * (cv + sp.z), 0.f);
                res.w = fmaxf(res.w - sc * (cv + sp.w), 0.f);
            }
            *reinterpret_cast<float4*>(&out[(size_t)row * D + col]) = res;
        }
    }
}

// ---------------- merged CSR build (both groupings in one pass) ----------------
__global__ __launch_bounds__(256) void hist_both(const int* __restrict__ rows,
                                                 const int* __restrict__ cols,
                                                 int* __restrict__ cntR,
                                                 int* __restrict__ cntC, int nnz) {
    int e = blockIdx.x * 256 + threadIdx.x;
    if (e < nnz) {
        atomicAdd(&cntR[rows[e]], 1);
        atomicAdd(&cntC[cols[e]], 1);
    }
}

__global__ __launch_bounds__(256) void scan_block2(
    const int* __restrict__ in0, int* __restrict__ out0, int* __restrict__ bs0,
    const int* __restrict__ in1, int* __restrict__ out1, int* __restrict__ bs1, int n)
{
    const int* in = blockIdx.y ? in1 : in0;
    int* out = blockIdx.y ? out1 : out0;
    int* bs  = blockIdx.y ? bs1 : bs0;
    __shared__ int s[256];
    int i = blockIdx.x * 256 + threadIdx.x;
    int v = (i < n) ? in[i] : 0;
    s[threadIdx.x] = v;
    __syncthreads();
#pragma unroll
    for (int d = 1; d < 256; d <<= 1) {
        int tv = (threadIdx.x >= d) ? s[threadIdx.x - d] : 0;
        __syncthreads();
        s[threadIdx.x] += tv;
        __syncthreads();
    }
    if (i < n) out[i] = s[threadIdx.x] - v;
    if (threadIdx.x == 255) bs[blockIdx.x] = s[255];
}

__global__ __launch_bounds__(256) void scan_bsum2(int* __restrict__ bs0,
                                                  int* __restrict__ bs1, int nb) {
    int* bs = blockIdx.x ? bs1 : bs0;
    __shared__ int s[256];
    int v = (threadIdx.x < nb) ? bs[threadIdx.x] : 0;
    s[threadIdx.x] = v;
    __syncthreads();
#pragma unroll
    for (int d = 1; d < 256; d <<= 1) {
        int tv = (threadIdx.x >= d) ? s[threadIdx.x - d] : 0;
        __syncthreads();
        s[threadIdx.x] += tv;
        __syncthreads();
    }
    if (threadIdx.x < nb) bs[threadIdx.x] = s[threadIdx.x] - v;
}

__global__ __launch_bounds__(256) void add_bsum2(int* __restrict__ o0, int* __restrict__ o1,
                                                 const int* __restrict__ bs0,
                                                 const int* __restrict__ bs1, int n) {
    int* o = blockIdx.y ? o1 : o0;
    const int* bs = blockIdx.y ? bs1 : bs0;
    int i = blockIdx.x * 256 + threadIdx.x;
    if (i < n) o[i] += bs[blockIdx.x];
}

// emits sorted (gather_col, val) pairs for both groupings
__global__ __launch_bounds__(256) void scatter_both(
    const int* __restrict__ rows, const int* __restrict__ cols,
    const float* __restrict__ vals,
    const int* __restrict__ offR, int* __restrict__ cR2, int2* __restrict__ pairsR,
    const int* __restrict__ offC, int* __restrict__ cC2, int2* __restrict__ pairsC,
    int nnz)
{
    int e = blockIdx.x * 256 + threadIdx.x;
    if (e >= nnz) return;
    int r = rows[e];
    int c = cols[e];
    int vbits = __float_as_int(vals[e]);
    int pr = offR[r] + atomicAdd(&cR2[r], 1);
    pairsR[pr] = make_int2(c, vbits);
    int pc = offC[c] + atomicAdd(&cC2[c], 1);
    pairsC[pc] = make_int2(r, vbits);
}

// ---------------- pairs-gather SpMM: out[row] = sum vals*X[col] ----------------
__global__ __launch_bounds__(256) void spmm_pairs(
    const int2* __restrict__ pairs, const int* __restrict__ off,
    const int* __restrict__ len, const float* __restrict__ X,
    float* __restrict__ out, int N)
{
    const int row = (blockIdx.x * 256 + threadIdx.x) >> 6;
    if (row >= N) return;
    const int lane = threadIdx.x & 63;
    const int s = off[row];
    const int L = len[row];

    float a0x = 0.f, a0y = 0.f, a1x = 0.f, a1y = 0.f;
    float a2x = 0.f, a2y = 0.f, a3x = 0.f, a3y = 0.f;
    int i = 0;
    for (; i + 3 < L; i += 4) {
        int2 p0 = pairs[s + i + 0];
        int2 p1 = pairs[s + i + 1];
        int2 p2 = pairs[s + i + 2];
        int2 p3 = pairs[s + i + 3];
        float2 x0 = *reinterpret_cast<const float2*>(&X[(size_t)p0.x * D + lane * 2]);
        float2 x1 = *reinterpret_cast<const float2*>(&X[(size_t)p1.x * D + lane * 2]);
        float2 x2 = *reinterpret_cast<const float2*>(&X[(size_t)p2.x * D + lane * 2]);
        float2 x3 = *reinterpret_cast<const float2*>(&X[(size_t)p3.x * D + lane * 2]);
        float v0 = __int_as_float(p0.y), v1 = __int_as_float(p1.y);
        float v2 = __int_as_float(p2.y), v3 = __int_as_float(p3.y);
        a0x += v0 * x0.x; a0y += v0 * x0.y;
        a1x += v1 * x1.x; a1y += v1 * x1.y;
        a2x += v2 * x2.x; a2y += v2 * x2.y;
        a3x += v3 * x3.x; a3y += v3 * x3.y;
    }
    for (; i < L; ++i) {
        int2 p0 = pairs[s + i];
        float v0 = __int_as_float(p0.y);
        float2 x0 = *reinterpret_cast<const float2*>(&X[(size_t)p0.x * D + lane * 2]);
        a0x += v0 * x0.x; a0y += v0 * x0.y;
    }
    float2 res = make_float2((a0x + a1x) + (a2x + a3x), (a0y + a1y) + (a2y + a3y));
    *reinterpret_cast<float2*>(&out[(size_t)row * D + lane * 2]) = res;
}

// ---------------- round-2 fallback kernels (perm path) ----------------
__global__ __launch_bounds__(256) void hist_kernel(const int* __restrict__ orow,
                                                   int* __restrict__ cnt, int nnz) {
    int e = blockIdx.x * 256 + threadIdx.x;
    if (e < nnz) atomicAdd(&cnt[orow[e]], 1);
}

__global__ __launch_bounds__(256) void scatter_kernel(const int* __restrict__ orow,
                                                      const int* __restrict__ off,
                                                      int* __restrict__ cnt2,
                                                      int* __restrict__ perm, int nnz) {
    int e = blockIdx.x * 256 + threadIdx.x;
    if (e < nnz) {
        int r = orow[e];
        int p = off[r] + atomicAdd(&cnt2[r], 1);
        perm[p] = e;
    }
}

__global__ __launch_bounds__(256) void spmm_gather(
    const float* __restrict__ vals, const int* __restrict__ gcol,
    const int* __restrict__ perm, const int* __restrict__ off,
    const int* __restrict__ len, const float* __restrict__ X,
    float* __restrict__ out, int N)
{
    const int row = (blockIdx.x * 256 + threadIdx.x) >> 6;
    if (row >= N) return;
    const int lane = threadIdx.x & 63;
    const int s = off[row];
    const int L = len[row];
    float ax = 0.f, ay = 0.f, bx = 0.f, by = 0.f;
    int i = 0;
    for (; i + 1 < L; i += 2) {
        int e0 = perm[s + i];
        int e1 = perm[s + i + 1];
        float v0 = vals[e0];
        float v1 = vals[e1];
        int c0 = gcol[e0];
        int c1 = gcol[e1];
        float2 x0 = *reinterpret_cast<const float2*>(&X[(size_t)c0 * D + lane * 2]);
        float2 x1 = *reinterpret_cast<const float2*>(&X[(size_t)c1 * D + lane * 2]);
        ax += v0 * x0.x; ay += v0 * x0.y;
        bx += v1 * x1.x; by += v1 * x1.y;
    }
    if (i < L) {
        int e0 = perm[s + i];
        float v0 = vals[e0];
        int c0 = gcol[e0];
        float2 x0 = *reinterpret_cast<const float2*>(&X[(size_t)c0 * D + lane * 2]);
        ax += v0 * x0.x; ay += v0 * x0.y;
    }
    *reinterpret_cast<float2*>(&out[(size_t)row * D + lane * 2]) =
        make_float2(ax + bx, ay + by);
}

__global__ __launch_bounds__(256) void spmm_atomic(
    const float* __restrict__ vals, const int* __restrict__ orow,
    const int* __restrict__ gcol, const float* __restrict__ Xm,
    float* __restrict__ outm, int nnz)
{
    const int gwave = (blockIdx.x * 256 + threadIdx.x) >> 6;
    const int lane = threadIdx.x & 63;
    const int e0 = gwave * 4;
#pragma unroll
    for (int i = 0; i < 4; ++i) {
        int e = e0 + i;
        if (e >= nnz) break;
        float v = vals[e];
        int r = orow[e];
        int c = gcol[e];
        float2 xv = *reinterpret_cast<const float2*>(&Xm[(size_t)c * D + lane * 2]);
        unsafeAtomicAdd(&outm[(size_t)r * D + lane * 2 + 0], v * xv.x);
        unsafeAtomicAdd(&outm[(size_t)r * D + lane * 2 + 1], v * xv.y);
    }
}

extern "C" void kernel_launch(void* const* d_in, const int* in_sizes, int n_in,
                              void* d_out, int out_size, void* d_ws, size_t ws_size,
                              hipStream_t stream) {
    const float* x      = (const float*)d_in[0];
    const float* y      = (const float*)d_in[1];
    const float* c      = (const float*)d_in[2];
    const float* b      = (const float*)d_in[3];
    const float* A_vals = (const float*)d_in[4];
    const int*   A_rows = (const int*)d_in[5];
    const int*   A_cols = (const int*)d_in[6];
    const float* Ukx_w  = (const float*)d_in[7];
    const float* Ukx_b  = (const float*)d_in[8];
    const float* Uky_w  = (const float*)d_in[9];
    const float* Uky_b  = (const float*)d_in[10];
    const float* tau    = (const float*)d_in[11];
    const float* Vky_w  = (const float*)d_in[12];
    const float* Vky_b  = (const float*)d_in[13];
    const float* Wkx_w  = (const float*)d_in[14];
    const float* Wkx_b  = (const float*)d_in[15];
    const float* Vkx_w  = (const float*)d_in[16];
    const float* Vkx_b  = (const float*)d_in[17];
    const float* sigma  = (const float*)d_in[18];

    const int N   = in_sizes[0] / D;   // 50000
    const int nnz = in_sizes[4];       // 1.6M
    const int nb  = (N + 255) / 256;

    float* out_x = (float*)d_out;
    float* out_y = out_x + (size_t)N * D;

    const int gemm_grid = (N + 63) / 64;
    const int egrid = (nnz + 255) / 256;
    const int ggrid = (N + 3) / 4;

    // ws layout (plan A):
    // tmp[N*D] | Wc[D*D] | bc[D] | cntR[N] cntC[N] cR2[N] cC2[N] | offR[N] offC[N]
    // | bsumR[256] bsumC[256] | pairsR[nnz int2] | pairsC[nnz int2]
    float* tmp = (float*)d_ws;
    float* Wc  = tmp + (size_t)N * D;
    float* bc  = Wc + D * D;
    int* cntR = (int*)(bc + D);
    int* cntC = cntR + N;
    int* cR2  = cntC + N;
    int* cC2  = cR2 + N;
    int* offR = cC2 + N;
    int* offC = offR + N;
    int* bsR  = offC + N;
    int* bsC  = bsR + 256;
    int2* pairsR = (int2*)(bsC + 256);
    int2* pairsC = pairsR + nnz;

    size_t needA = ((size_t)N * D + D * D + D + 6 * (size_t)N + 512 + 4 * (size_t)nnz) * 4;
    size_t needB = ((size_t)N * D + D * D + D + 3 * (size_t)N + 256 + (size_t)nnz) * 4;

    combine_w_kernel<<<(D * D + 255) / 256, 256, 0, stream>>>(Vkx_w, Wkx_w, Vkx_b, Wkx_b, Wc, bc);

    if (ws_size >= needA && nb <= 256) {
        // ---- merged CSR build (independent of GEMMs) ----
        hipMemsetAsync(cntR, 0, 4 * (size_t)N * sizeof(int), stream);  // cntR,cntC,cR2,cC2
        hist_both<<<egrid, 256, 0, stream>>>(A_rows, A_cols, cntR, cntC, nnz);
        {
            dim3 g(nb, 2);
            scan_block2<<<g, 256, 0, stream>>>(cntR, offR, bsR, cntC, offC, bsC, N);
            scan_bsum2<<<2, 256, 0, stream>>>(bsR, bsC, nb);
            add_bsum2<<<g, 256, 0, stream>>>(offR, offC, bsR, bsC, N);
        }
        scatter_both<<<egrid, 256, 0, stream>>>(A_rows, A_cols, A_vals,
                                                offR, cR2, pairsR, offC, cC2, pairsC, nnz);

        // uy = y @ Uky^T + b  -> staged in out_y
        gemm_fused<0><<<gemm_grid, 256, 0, stream>>>(y, Uky_w, Uky_b, nullptr, nullptr, nullptr, out_y, N);
        // at_uy -> out_x  (grouping by A_cols, gather col = A_rows)
        spmm_pairs<<<ggrid, 256, 0, stream>>>(pairsC, offC, cntC, out_y, out_x, N);
        // x_new -> out_x (in place)
        gemm_fused<1><<<gemm_grid, 256, 0, stream>>>(x, Ukx_w, Ukx_b, c, out_x, tau, out_x, N);
        // zx -> tmp
        gemm_fused<0><<<gemm_grid, 256, 0, stream>>>(out_x, Wc, bc, nullptr, nullptr, nullptr, tmp, N);
        // az -> out_y  (grouping by A_rows, gather col = A_cols)
        spmm_pairs<<<ggrid, 256, 0, stream>>>(pairsR, offR, cntR, tmp, out_y, N);
        // y_new -> out_y (in place)
        gemm_fused<2><<<gemm_grid, 256, 0, stream>>>(y, Vky_w, Vky_b, b, out_y, sigma, out_y, N);
    } else if (ws_size >= needB && nb <= 256) {
        // ---- round-2 perm path ----
        int* cnt  = (int*)(bc + D);
        int* cnt2 = cnt + N;
        int* off  = cnt2 + N;
        int* bsum = off + N;
        int* perm = bsum + 256;
        dim3 g1(nb, 1);

        gemm_fused<0><<<gemm_grid, 256, 0, stream>>>(y, Uky_w, Uky_b, nullptr, nullptr, nullptr, out_y, N);

        hipMemsetAsync(cnt, 0, 2 * (size_t)N * sizeof(int), stream);
        hist_kernel<<<egrid, 256, 0, stream>>>(A_cols, cnt, nnz);
        scan_block2<<<g1, 256, 0, stream>>>(cnt, off, bsum, cnt, off, bsum, N);
        scan_bsum2<<<1, 256, 0, stream>>>(bsum, bsum, nb);
        add_bsum2<<<g1, 256, 0, stream>>>(off, off, bsum, bsum, N);
        scatter_kernel<<<egrid, 256, 0, stream>>>(A_cols, off, cnt2, perm, nnz);
        spmm_gather<<<ggrid, 256, 0, stream>>>(A_vals, A_rows, perm, off, cnt, out_y, out_x, N);

        gemm_fused<1><<<gemm_grid, 256, 0, stream>>>(x, Ukx_w, Ukx_b, c, out_x, tau, out_x, N);
        gemm_fused<0><<<gemm_grid, 256, 0, stream>>>(out_x, Wc, bc, nullptr, nullptr, nullptr, tmp, N);

        hipMemsetAsync(cnt, 0, 2 * (size_t)N * sizeof(int), stream);
        hist_kernel<<<egrid, 256, 0, stream>>>(A_rows, cnt, nnz);
        scan_block2<<<g1, 256, 0, stream>>>(cnt, off, bsum, cnt, off, bsum, N);
        scan_bsum2<<<1, 256, 0, stream>>>(bsum, bsum, nb);
        add_bsum2<<<g1, 256, 0, stream>>>(off, off, bsum, bsum, N);
        scatter_kernel<<<egrid, 256, 0, stream>>>(A_rows, off, cnt2, perm, nnz);
        spmm_gather<<<ggrid, 256, 0, stream>>>(A_vals, A_cols, perm, off, cnt, tmp, out_y, N);

        gemm_fused<2><<<gemm_grid, 256, 0, stream>>>(y, Vky_w, Vky_b, b, out_y, sigma, out_y, N);
    } else {
        // ---- atomic fallback ----
        const int spmm_grid = (nnz + 15) / 16;
        gemm_fused<0><<<gemm_grid, 256, 0, stream>>>(y, Uky_w, Uky_b, nullptr, nullptr, nullptr, tmp, N);
        hipMemsetAsync(out_x, 0, (size_t)N * D * sizeof(float), stream);
        spmm_atomic<<<spmm_grid, 256, 0, stream>>>(A_vals, A_cols, A_rows, tmp, out_x, nnz);
        gemm_fused<1><<<gemm_grid, 256, 0, stream>>>(x, Ukx_w, Ukx_b, c, out_x, tau, out_x, N);
        gemm_fused<0><<<gemm_grid, 256, 0, stream>>>(out_x, Wc, bc, nullptr, nullptr, nullptr, tmp, N);
        hipMemsetAsync(out_y, 0, (size_t)N * D * sizeof(float), stream);
        spmm_atomic<<<spmm_grid, 256, 0, stream>>>(A_vals, A_rows, A_cols, tmp, out_y, nnz);
        gemm_fused<2><<<gemm_grid, 256, 0, stream>>>(y, Vky_w, Vky_b, b, out_y, sigma, out_y, N);
    }
}

// Round 4
// 637.461 us; speedup vs baseline: 4.3362x; 1.0227x over previous
//
#include <hip/hip_runtime.h>

#define D 128
#define NSLICE 8

// ---------------- setup: transpose weights + fold Wc = Vkx - 2*Wkx ----------------
// grid.x = 4: 0->UkyT, 1->UkxT, 2->VkyT, 3->WcT (+bc)
__global__ __launch_bounds__(256) void setup_weights(
    const float* __restrict__ Uky, const float* __restrict__ Ukx,
    const float* __restrict__ Vky, const float* __restrict__ Vkx,
    const float* __restrict__ Wkx, const float* __restrict__ Vkx_b,
    const float* __restrict__ Wkx_b,
    float* __restrict__ UkyT, float* __restrict__ UkxT,
    float* __restrict__ VkyT, float* __restrict__ WcT, float* __restrict__ bc)
{
    const int m = blockIdx.x;
    const float* src = (m == 0) ? Uky : (m == 1) ? Ukx : (m == 2) ? Vky : nullptr;
    float* dst = (m == 0) ? UkyT : (m == 1) ? UkxT : (m == 2) ? VkyT : WcT;
    for (int i = threadIdx.x; i < D * D; i += 256) {
        int k = i >> 7, d = i & 127;
        float v;
        if (m == 3) v = Vkx[d * D + k] - 2.0f * Wkx[d * D + k];
        else        v = src[d * D + k];
        dst[i] = v;   // dst[k][d] = W[d][k]
    }
    if (m == 3 && threadIdx.x < D)
        bc[threadIdx.x] = Vkx_b[threadIdx.x] - 2.0f * Wkx_b[threadIdx.x];
}

// ---------------- fused GEMM v2: out = epi(X @ W^T + bias), takes W pre-transposed ----
// 64 rows x 128 cols per block (256 thr); per thread 4 rows x 8 cols.
template <int EPI>
__global__ __launch_bounds__(256) void gemm_v2(
    const float* __restrict__ X, const float* __restrict__ WT,   // WT[k][d]
    const float* __restrict__ bias, const float* __restrict__ colvec,
    const float* __restrict__ spout, const float* __restrict__ scal,
    float* __restrict__ out, int N)
{
    __shared__ float Xs[64][D + 4];
    __shared__ float Wt[64][D + 4];
    const int t = threadIdx.x;
    const int block_row = blockIdx.x * 64;

    // stage X tile once (all 128 k)
#pragma unroll
    for (int i = 0; i < 8; ++i) {
        int f = t + i * 256;
        int r = f >> 5;
        int k4 = (f & 31) << 2;
        float4 g = make_float4(0.f, 0.f, 0.f, 0.f);
        int row = block_row + r;
        if (row < N) g = *reinterpret_cast<const float4*>(&X[(size_t)row * D + k4]);
        *reinterpret_cast<float4*>(&Xs[r][k4]) = g;
    }

    const int cg = t & 15;
    const int rp = t >> 4;
    const int r0 = rp * 4;
    const int c0 = cg * 4, c1 = 64 + cg * 4;

    float acc[4][8] = {{0.f}};

    for (int kb = 0; kb < D; kb += 64) {
        __syncthreads();
        // stage Wt[kk][d] = WT[kb+kk][d] -- straight float4 copy, no transpose
#pragma unroll
        for (int i = 0; i < 8; ++i) {
            int f = t + i * 256;
            int kk = f >> 5;
            int d4 = (f & 31) << 2;
            float4 g = *reinterpret_cast<const float4*>(&WT[(size_t)(kb + kk) * D + d4]);
            *reinterpret_cast<float4*>(&Wt[kk][d4]) = g;
        }
        __syncthreads();
#pragma unroll 2
        for (int k4 = 0; k4 < 64; k4 += 4) {
            float4 xr[4];
#pragma unroll
            for (int j = 0; j < 4; ++j)
                xr[j] = *reinterpret_cast<const float4*>(&Xs[r0 + j][kb + k4]);
#pragma unroll
            for (int q = 0; q < 4; ++q) {
                const float4 w0 = *reinterpret_cast<const float4*>(&Wt[k4 + q][c0]);
                const float4 w1 = *reinterpret_cast<const float4*>(&Wt[k4 + q][c1]);
#pragma unroll
                for (int j = 0; j < 4; ++j) {
                    const float xv = (q == 0) ? xr[j].x : (q == 1) ? xr[j].y
                                   : (q == 2) ? xr[j].z : xr[j].w;
                    acc[j][0] += xv * w0.x; acc[j][1] += xv * w0.y;
                    acc[j][2] += xv * w0.z; acc[j][3] += xv * w0.w;
                    acc[j][4] += xv * w1.x; acc[j][5] += xv * w1.y;
                    acc[j][6] += xv * w1.z; acc[j][7] += xv * w1.w;
                }
            }
        }
    }

    const float sc = (EPI == 0) ? 0.f : scal[0];
    const float4 bias0 = *reinterpret_cast<const float4*>(&bias[c0]);
    const float4 bias1 = *reinterpret_cast<const float4*>(&bias[c1]);

#pragma unroll
    for (int j = 0; j < 4; ++j) {
        const int row = block_row + r0 + j;
        if (row >= N) continue;
        const float cv = (EPI == 0) ? 0.f : colvec[row];
#pragma unroll
        for (int h = 0; h < 2; ++h) {
            const int col = (h == 0) ? c0 : c1;
            const float4 bs = (h == 0) ? bias0 : bias1;
            float4 res;
            res.x = acc[j][h * 4 + 0] + bs.x;
            res.y = acc[j][h * 4 + 1] + bs.y;
            res.z = acc[j][h * 4 + 2] + bs.z;
            res.w = acc[j][h * 4 + 3] + bs.w;
            if (EPI == 1) {
                float4 sp = *reinterpret_cast<const float4*>(&spout[(size_t)row * D + col]);
                res.x = fmaxf(res.x - sc * (cv - sp.x), 0.f);
                res.y = fmaxf(res.y - sc * (cv - sp.y), 0.f);
                res.z = fmaxf(res.z - sc * (cv - sp.z), 0.f);
                res.w = fmaxf(res.w - sc * (cv - sp.w), 0.f);
            } else if (EPI == 2) {
                float4 sp = *reinterpret_cast<const float4*>(&spout[(size_t)row * D + col]);
                res.x = fmaxf(res.x - sc * (cv + sp.x), 0.f);
                res.y = fmaxf(res.y - sc * (cv + sp.y), 0.f);
                res.z = fmaxf(res.z - sc * (cv + sp.z), 0.f);
                res.w = fmaxf(res.w - sc * (cv + sp.w), 0.f);
            }
            *reinterpret_cast<float4*>(&out[(size_t)row * D + col]) = res;
        }
    }
}

// ---------------- CSR build ----------------
__global__ __launch_bounds__(256) void hist_both(const int* __restrict__ rows,
                                                 const int* __restrict__ cols,
                                                 int* __restrict__ cntR,
                                                 int* __restrict__ cntC, int nnz) {
    int e = blockIdx.x * 256 + threadIdx.x;
    if (e < nnz) {
        atomicAdd(&cntR[rows[e]], 1);
        atomicAdd(&cntC[cols[e]], 1);
    }
}

__global__ __launch_bounds__(256) void scan_block2(
    const int* __restrict__ in0, int* __restrict__ out0, int* __restrict__ bs0,
    const int* __restrict__ in1, int* __restrict__ out1, int* __restrict__ bs1, int n)
{
    const int* in = blockIdx.y ? in1 : in0;
    int* out = blockIdx.y ? out1 : out0;
    int* bs  = blockIdx.y ? bs1 : bs0;
    __shared__ int s[256];
    int i = blockIdx.x * 256 + threadIdx.x;
    int v = (i < n) ? in[i] : 0;
    s[threadIdx.x] = v;
    __syncthreads();
#pragma unroll
    for (int d = 1; d < 256; d <<= 1) {
        int tv = (threadIdx.x >= d) ? s[threadIdx.x - d] : 0;
        __syncthreads();
        s[threadIdx.x] += tv;
        __syncthreads();
    }
    if (i < n) out[i] = s[threadIdx.x] - v;
    if (threadIdx.x == 255) bs[blockIdx.x] = s[255];
}

__global__ __launch_bounds__(256) void scan_bsum2(int* __restrict__ bs0,
                                                  int* __restrict__ bs1, int nb) {
    int* bs = blockIdx.x ? bs1 : bs0;
    __shared__ int s[256];
    int v = (threadIdx.x < nb) ? bs[threadIdx.x] : 0;
    s[threadIdx.x] = v;
    __syncthreads();
#pragma unroll
    for (int d = 1; d < 256; d <<= 1) {
        int tv = (threadIdx.x >= d) ? s[threadIdx.x - d] : 0;
        __syncthreads();
        s[threadIdx.x] += tv;
        __syncthreads();
    }
    if (threadIdx.x < nb) bs[threadIdx.x] = s[threadIdx.x] - v;
}

__global__ __launch_bounds__(256) void add_bsum2(int* __restrict__ o0, int* __restrict__ o1,
                                                 const int* __restrict__ bs0,
                                                 const int* __restrict__ bs1, int n) {
    int* o = blockIdx.y ? o1 : o0;
    const int* bs = blockIdx.y ? bs1 : bs0;
    int i = blockIdx.x * 256 + threadIdx.x;
    if (i < n) o[i] += bs[blockIdx.x];
}

// ---------------- destination-sliced scatter (L2-local writes) ----------------
// grid.x = NSLICE * nchunk; slice = bid & 7 -> XCD affinity via round-robin dispatch.
// Slice s commits only records whose destination row is in [lo, hi): the 3.2 MB
// destination window stays resident in that XCD's L2, so lines are fully
// assembled before writeback (kills the 64B-line write amplification).
__global__ __launch_bounds__(256) void scatter_sliced(
    const int* __restrict__ rows, const int* __restrict__ cols,
    const float* __restrict__ vals,
    const int* __restrict__ offR, int* __restrict__ cR2, int2* __restrict__ pairsR,
    const int* __restrict__ offC, int* __restrict__ cC2, int2* __restrict__ pairsC,
    int nnz, int N, int ce)
{
    const int slice  = blockIdx.x & (NSLICE - 1);
    const int chunk  = blockIdx.x >> 3;
    const int rps    = (N + NSLICE - 1) / NSLICE;
    const int lo     = slice * rps;
    const int hi     = min(N, lo + rps);
    const int e0     = chunk * ce;
    const int e1     = min(nnz, e0 + ce);

    for (int eb = e0 + threadIdx.x * 4; eb < e1; eb += 256 * 4) {
        int rr[4], cc[4];
        float vv[4];
        if (eb + 3 < e1) {
            int4 r4 = *reinterpret_cast<const int4*>(&rows[eb]);
            int4 c4 = *reinterpret_cast<const int4*>(&cols[eb]);
            float4 v4 = *reinterpret_cast<const float4*>(&vals[eb]);
            rr[0] = r4.x; rr[1] = r4.y; rr[2] = r4.z; rr[3] = r4.w;
            cc[0] = c4.x; cc[1] = c4.y; cc[2] = c4.z; cc[3] = c4.w;
            vv[0] = v4.x; vv[1] = v4.y; vv[2] = v4.z; vv[3] = v4.w;
        } else {
#pragma unroll
            for (int u = 0; u < 4; ++u) {
                int e = eb + u;
                rr[u] = (e < e1) ? rows[e] : -1;
                cc[u] = (e < e1) ? cols[e] : -1;
                vv[u] = (e < e1) ? vals[e] : 0.f;
            }
        }
#pragma unroll
        for (int u = 0; u < 4; ++u) {
            int r = rr[u], c = cc[u];
            int vbits = __float_as_int(vv[u]);
            if (r >= lo && r < hi) {
                int p = offR[r] + atomicAdd(&cR2[r], 1);
                pairsR[p] = make_int2(c, vbits);
            }
            if (c >= lo && c < hi) {
                int p = offC[c] + atomicAdd(&cC2[c], 1);
                pairsC[p] = make_int2(r, vbits);
            }
        }
    }
}

// ---------------- pairs-gather SpMM: out[row] = sum vals*X[col] ----------------
__global__ __launch_bounds__(256) void spmm_pairs(
    const int2* __restrict__ pairs, const int* __restrict__ off,
    const int* __restrict__ len, const float* __restrict__ X,
    float* __restrict__ out, int N)
{
    const int row = (blockIdx.x * 256 + threadIdx.x) >> 6;
    if (row >= N) return;
    const int lane = threadIdx.x & 63;
    const int s = off[row];
    const int L = len[row];

    float a0x = 0.f, a0y = 0.f, a1x = 0.f, a1y = 0.f;
    float a2x = 0.f, a2y = 0.f, a3x = 0.f, a3y = 0.f;
    int i = 0;
    for (; i + 3 < L; i += 4) {
        int2 p0 = pairs[s + i + 0];
        int2 p1 = pairs[s + i + 1];
        int2 p2 = pairs[s + i + 2];
        int2 p3 = pairs[s + i + 3];
        float2 x0 = *reinterpret_cast<const float2*>(&X[(size_t)p0.x * D + lane * 2]);
        float2 x1 = *reinterpret_cast<const float2*>(&X[(size_t)p1.x * D + lane * 2]);
        float2 x2 = *reinterpret_cast<const float2*>(&X[(size_t)p2.x * D + lane * 2]);
        float2 x3 = *reinterpret_cast<const float2*>(&X[(size_t)p3.x * D + lane * 2]);
        float v0 = __int_as_float(p0.y), v1 = __int_as_float(p1.y);
        float v2 = __int_as_float(p2.y), v3 = __int_as_float(p3.y);
        a0x += v0 * x0.x; a0y += v0 * x0.y;
        a1x += v1 * x1.x; a1y += v1 * x1.y;
        a2x += v2 * x2.x; a2y += v2 * x2.y;
        a3x += v3 * x3.x; a3y += v3 * x3.y;
    }
    for (; i < L; ++i) {
        int2 p0 = pairs[s + i];
        float v0 = __int_as_float(p0.y);
        float2 x0 = *reinterpret_cast<const float2*>(&X[(size_t)p0.x * D + lane * 2]);
        a0x += v0 * x0.x; a0y += v0 * x0.y;
    }
    float2 res = make_float2((a0x + a1x) + (a2x + a3x), (a0y + a1y) + (a2y + a3y));
    *reinterpret_cast<float2*>(&out[(size_t)row * D + lane * 2]) = res;
}

// ---------------- fallback kernels (perm path / atomic path) ----------------
__global__ __launch_bounds__(256) void hist_kernel(const int* __restrict__ orow,
                                                   int* __restrict__ cnt, int nnz) {
    int e = blockIdx.x * 256 + threadIdx.x;
    if (e < nnz) atomicAdd(&cnt[orow[e]], 1);
}

__global__ __launch_bounds__(256) void scatter_kernel(const int* __restrict__ orow,
                                                      const int* __restrict__ off,
                                                      int* __restrict__ cnt2,
                                                      int* __restrict__ perm, int nnz) {
    int e = blockIdx.x * 256 + threadIdx.x;
    if (e < nnz) {
        int r = orow[e];
        int p = off[r] + atomicAdd(&cnt2[r], 1);
        perm[p] = e;
    }
}

__global__ __launch_bounds__(256) void spmm_gather(
    const float* __restrict__ vals, const int* __restrict__ gcol,
    const int* __restrict__ perm, const int* __restrict__ off,
    const int* __restrict__ len, const float* __restrict__ X,
    float* __restrict__ out, int N)
{
    const int row = (blockIdx.x * 256 + threadIdx.x) >> 6;
    if (row >= N) return;
    const int lane = threadIdx.x & 63;
    const int s = off[row];
    const int L = len[row];
    float ax = 0.f, ay = 0.f, bx = 0.f, by = 0.f;
    int i = 0;
    for (; i + 1 < L; i += 2) {
        int e0 = perm[s + i];
        int e1 = perm[s + i + 1];
        float v0 = vals[e0];
        float v1 = vals[e1];
        int c0 = gcol[e0];
        int c1 = gcol[e1];
        float2 x0 = *reinterpret_cast<const float2*>(&X[(size_t)c0 * D + lane * 2]);
        float2 x1 = *reinterpret_cast<const float2*>(&X[(size_t)c1 * D + lane * 2]);
        ax += v0 * x0.x; ay += v0 * x0.y;
        bx += v1 * x1.x; by += v1 * x1.y;
    }
    if (i < L) {
        int e0 = perm[s + i];
        float v0 = vals[e0];
        int c0 = gcol[e0];
        float2 x0 = *reinterpret_cast<const float2*>(&X[(size_t)c0 * D + lane * 2]);
        ax += v0 * x0.x; ay += v0 * x0.y;
    }
    *reinterpret_cast<float2*>(&out[(size_t)row * D + lane * 2]) =
        make_float2(ax + bx, ay + by);
}

__global__ __launch_bounds__(256) void spmm_atomic(
    const float* __restrict__ vals, const int* __restrict__ orow,
    const int* __restrict__ gcol, const float* __restrict__ Xm,
    float* __restrict__ outm, int nnz)
{
    const int gwave = (blockIdx.x * 256 + threadIdx.x) >> 6;
    const int lane = threadIdx.x & 63;
    const int e0 = gwave * 4;
#pragma unroll
    for (int i = 0; i < 4; ++i) {
        int e = e0 + i;
        if (e >= nnz) break;
        float v = vals[e];
        int r = orow[e];
        int c = gcol[e];
        float2 xv = *reinterpret_cast<const float2*>(&Xm[(size_t)c * D + lane * 2]);
        unsafeAtomicAdd(&outm[(size_t)r * D + lane * 2 + 0], v * xv.x);
        unsafeAtomicAdd(&outm[(size_t)r * D + lane * 2 + 1], v * xv.y);
    }
}

extern "C" void kernel_launch(void* const* d_in, const int* in_sizes, int n_in,
                              void* d_out, int out_size, void* d_ws, size_t ws_size,
                              hipStream_t stream) {
    const float* x      = (const float*)d_in[0];
    const float* y      = (const float*)d_in[1];
    const float* c      = (const float*)d_in[2];
    const float* b      = (const float*)d_in[3];
    const float* A_vals = (const float*)d_in[4];
    const int*   A_rows = (const int*)d_in[5];
    const int*   A_cols = (const int*)d_in[6];
    const float* Ukx_w  = (const float*)d_in[7];
    const float* Ukx_b  = (const float*)d_in[8];
    const float* Uky_w  = (const float*)d_in[9];
    const float* Uky_b  = (const float*)d_in[10];
    const float* tau    = (const float*)d_in[11];
    const float* Vky_w  = (const float*)d_in[12];
    const float* Vky_b  = (const float*)d_in[13];
    const float* Wkx_w  = (const float*)d_in[14];
    const float* Wkx_b  = (const float*)d_in[15];
    const float* Vkx_w  = (const float*)d_in[16];
    const float* Vkx_b  = (const float*)d_in[17];
    const float* sigma  = (const float*)d_in[18];

    const int N   = in_sizes[0] / D;   // 50000
    const int nnz = in_sizes[4];       // 1.6M
    const int nb  = (N + 255) / 256;

    float* out_x = (float*)d_out;
    float* out_y = out_x + (size_t)N * D;

    const int gemm_grid = (N + 63) / 64;
    const int egrid = (nnz + 255) / 256;
    const int ggrid = (N + 3) / 4;

    // ws layout (plan A):
    // tmp[N*D] | UkyT | UkxT | VkyT | WcT (4x D*D) | bc[D] |
    // cntR[N] cntC[N] cR2[N] cC2[N] offR[N] offC[N] | bsR[256] bsC[256] |
    // pairsR[nnz int2] | pairsC[nnz int2]
    float* tmp  = (float*)d_ws;
    float* UkyT = tmp + (size_t)N * D;
    float* UkxT = UkyT + D * D;
    float* VkyT = UkxT + D * D;
    float* WcT  = VkyT + D * D;
    float* bc   = WcT + D * D;
    int* cntR = (int*)(bc + D);
    int* cntC = cntR + N;
    int* cR2  = cntC + N;
    int* cC2  = cR2 + N;
    int* offR = cC2 + N;
    int* offC = offR + N;
    int* bsR  = offC + N;
    int* bsC  = bsR + 256;
    int2* pairsR = (int2*)(bsC + 256);
    int2* pairsC = pairsR + nnz;

    size_t needA = ((size_t)N * D + 4 * D * D + D + 6 * (size_t)N + 512 + 4 * (size_t)nnz) * 4;
    size_t needB = ((size_t)N * D + 4 * D * D + D + 3 * (size_t)N + 256 + (size_t)nnz) * 4;

    // weights: transpose + fold (all paths use gemm_v2)
    setup_weights<<<4, 256, 0, stream>>>(Uky_w, Ukx_w, Vky_w, Vkx_w, Wkx_w,
                                         Vkx_b, Wkx_b, UkyT, UkxT, VkyT, WcT, bc);

    if (ws_size >= needA && nb <= 256) {
        // ---- CSR build ----
        hipMemsetAsync(cntR, 0, 4 * (size_t)N * sizeof(int), stream);  // cntR,cntC,cR2,cC2
        hist_both<<<egrid, 256, 0, stream>>>(A_rows, A_cols, cntR, cntC, nnz);
        {
            dim3 g(nb, 2);
            scan_block2<<<g, 256, 0, stream>>>(cntR, offR, bsR, cntC, offC, bsC, N);
            scan_bsum2<<<2, 256, 0, stream>>>(bsR, bsC, nb);
            add_bsum2<<<g, 256, 0, stream>>>(offR, offC, bsR, bsC, N);
        }
        {
            const int NCHUNK = 128;
            int ce = ((nnz + NCHUNK - 1) / NCHUNK + 3) & ~3;   // mult of 4 keeps int4 alignment
            scatter_sliced<<<NSLICE * NCHUNK, 256, 0, stream>>>(
                A_rows, A_cols, A_vals, offR, cR2, pairsR, offC, cC2, pairsC, nnz, N, ce);
        }

        // uy = y @ Uky^T + b  -> staged in out_y
        gemm_v2<0><<<gemm_grid, 256, 0, stream>>>(y, UkyT, Uky_b, nullptr, nullptr, nullptr, out_y, N);
        // at_uy -> out_x  (grouped by A_cols, gather col = A_rows)
        spmm_pairs<<<ggrid, 256, 0, stream>>>(pairsC, offC, cntC, out_y, out_x, N);
        // x_new -> out_x (in place)
        gemm_v2<1><<<gemm_grid, 256, 0, stream>>>(x, UkxT, Ukx_b, c, out_x, tau, out_x, N);
        // zx -> tmp
        gemm_v2<0><<<gemm_grid, 256, 0, stream>>>(out_x, WcT, bc, nullptr, nullptr, nullptr, tmp, N);
        // az -> out_y  (grouped by A_rows, gather col = A_cols; uy is dead)
        spmm_pairs<<<ggrid, 256, 0, stream>>>(pairsR, offR, cntR, tmp, out_y, N);
        // y_new -> out_y (in place)
        gemm_v2<2><<<gemm_grid, 256, 0, stream>>>(y, VkyT, Vky_b, b, out_y, sigma, out_y, N);
    } else if (ws_size >= needB && nb <= 256) {
        // ---- perm path ----
        int* cnt  = (int*)(bc + D);
        int* cnt2 = cnt + N;
        int* off  = cnt2 + N;
        int* bsum = off + N;
        int* perm = bsum + 256;
        dim3 g1(nb, 1);

        gemm_v2<0><<<gemm_grid, 256, 0, stream>>>(y, UkyT, Uky_b, nullptr, nullptr, nullptr, out_y, N);

        hipMemsetAsync(cnt, 0, 2 * (size_t)N * sizeof(int), stream);
        hist_kernel<<<egrid, 256, 0, stream>>>(A_cols, cnt, nnz);
        scan_block2<<<g1, 256, 0, stream>>>(cnt, off, bsum, cnt, off, bsum, N);
        scan_bsum2<<<1, 256, 0, stream>>>(bsum, bsum, nb);
        add_bsum2<<<g1, 256, 0, stream>>>(off, off, bsum, bsum, N);
        scatter_kernel<<<egrid, 256, 0, stream>>>(A_cols, off, cnt2, perm, nnz);
        spmm_gather<<<ggrid, 256, 0, stream>>>(A_vals, A_rows, perm, off, cnt, out_y, out_x, N);

        gemm_v2<1><<<gemm_grid, 256, 0, stream>>>(x, UkxT, Ukx_b, c, out_x, tau, out_x, N);
        gemm_v2<0><<<gemm_grid, 256, 0, stream>>>(out_x, WcT, bc, nullptr, nullptr, nullptr, tmp, N);

        hipMemsetAsync(cnt, 0, 2 * (size_t)N * sizeof(int), stream);
        hist_kernel<<<egrid, 256, 0, stream>>>(A_rows, cnt, nnz);
        scan_block2<<<g1, 256, 0, stream>>>(cnt, off, bsum, cnt, off, bsum, N);
        scan_bsum2<<<1, 256, 0, stream>>>(bsum, bsum, nb);
        add_bsum2<<<g1, 256, 0, stream>>>(off, off, bsum, bsum, N);
        scatter_kernel<<<egrid, 256, 0, stream>>>(A_rows, off, cnt2, perm, nnz);
        spmm_gather<<<ggrid, 256, 0, stream>>>(A_vals, A_cols, perm, off, cnt, tmp, out_y, N);

        gemm_v2<2><<<gemm_grid, 256, 0, stream>>>(y, VkyT, Vky_b, b, out_y, sigma, out_y, N);
    } else {
        // ---- atomic fallback ----
        const int spmm_grid = (nnz + 15) / 16;
        gemm_v2<0><<<gemm_grid, 256, 0, stream>>>(y, UkyT, Uky_b, nullptr, nullptr, nullptr, tmp, N);
        hipMemsetAsync(out_x, 0, (size_t)N * D * sizeof(float), stream);
        spmm_atomic<<<spmm_grid, 256, 0, stream>>>(A_vals, A_cols, A_rows, tmp, out_x, nnz);
        gemm_v2<1><<<gemm_grid, 256, 0, stream>>>(x, UkxT, Ukx_b, c, out_x, tau, out_x, N);
        gemm_v2<0><<<gemm_grid, 256, 0, stream>>>(out_x, WcT, bc, nullptr, nullptr, nullptr, tmp, N);
        hipMemsetAsync(out_y, 0, (size_t)N * D * sizeof(float), stream);
        spmm_atomic<<<spmm_grid, 256, 0, stream>>>(A_vals, A_rows, A_cols, tmp, out_y, nnz);
        gemm_v2<2><<<gemm_grid, 256, 0, stream>>>(y, VkyT, Vky_b, b, out_y, sigma, out_y, N);
    }
}